// Round 2
// baseline (8215.991 us; speedup 1.0000x reference)
//
#include <hip/hip_runtime.h>
#include <hip/hip_cooperative_groups.h>

namespace cg = cooperative_groups;

#define HW 196
#define WIDTH 14
#define T_STEPS 32
#define KC 64      // centers / GRU channels
#define DD 512     // reduced dim
#define CIN 1024
#define NFR 256    // B*T
#define NB 8       // videos

using f16x8 = __attribute__((ext_vector_type(8))) _Float16;
using f32x4 = __attribute__((ext_vector_type(4))) float;

// ---------------------------------------------------------------------------
// fp16 MFMA 1x1 conv: out[n][m][p] = bias[m] + sum_c W[m][c]*in[n][c][p]
// BM x 224 tile per block (one frame), BK=32, 4 waves (2x2), 16x16x32_f16.
// ---------------------------------------------------------------------------
template<int BM>
__global__ __launch_bounds__(256)
void conv1x1_mfma(const float* __restrict__ in, const float* __restrict__ W,
                  const float* __restrict__ bias, float* __restrict__ out,
                  int C, int M) {
  constexpr int MF = BM / 32;           // m-frags per wave
  __shared__ _Float16 sA[BM][40];       // [m][k] pad->40 (2-way max on b128 reads)
  __shared__ _Float16 sX[224][40];      // [p][k] transposed X tile
  const int tid = threadIdx.x;
  const int lane = tid & 63;
  const int wv = tid >> 6;
  const int wm = wv >> 1, wn = wv & 1;
  const int l16 = lane & 15, lhi = lane >> 4;

  int n, mt;
  if (BM == 128) {
    // XCD-grouped swizzle: 4 m-blocks of a frame land on one XCD, adjacent
    // in dispatch order, sharing X_n (803KB) via that XCD's 4MB L2.
    int xcd = blockIdx.x & 7;
    int idx = blockIdx.x >> 3;          // 0..127
    n = xcd * 32 + (idx >> 2);
    mt = idx & 3;
  } else {
    n = blockIdx.x; mt = 0;
  }
  const int m0 = mt * BM;
  const float* inN = in + (size_t)n * C * HW;

  f32x4 acc[MF][7];
  #pragma unroll
  for (int i = 0; i < MF; ++i)
    #pragma unroll
    for (int f = 0; f < 7; ++f) acc[i][f] = {0.f, 0.f, 0.f, 0.f};

  for (int c0 = 0; c0 < C; c0 += 32) {
    // stage W tile (BM x 32), f32 -> f16
    for (int e = tid * 2; e < BM * 32; e += 512) {
      int r = e >> 5, kk = e & 31;
      float2 w2 = *reinterpret_cast<const float2*>(&W[(size_t)(m0 + r) * C + c0 + kk]);
      sA[r][kk] = (_Float16)w2.x;
      sA[r][kk + 1] = (_Float16)w2.y;
    }
    // stage X tile transposed: sX[p][k] = in[c0+k][p]; one p per thread,
    // 8 coalesced f32 loads -> one b128 ds_write (conflict-light: stride 80B)
    if (tid < 224) {
      #pragma unroll
      for (int g = 0; g < 4; ++g) {
        f16x8 v;
        #pragma unroll
        for (int j = 0; j < 8; ++j) {
          float xv = (tid < HW) ? inN[(size_t)(c0 + g * 8 + j) * HW + tid] : 0.0f;
          v[j] = (_Float16)xv;
        }
        *reinterpret_cast<f16x8*>(&sX[tid][g * 8]) = v;
      }
    }
    __syncthreads();
    f16x8 af[MF];
    #pragma unroll
    for (int i = 0; i < MF; ++i)
      af[i] = *reinterpret_cast<const f16x8*>(&sA[wm * (16 * MF) + i * 16 + l16][lhi * 8]);
    #pragma unroll
    for (int f = 0; f < 7; ++f) {
      f16x8 bf = *reinterpret_cast<const f16x8*>(&sX[wn * 112 + f * 16 + l16][lhi * 8]);
      #pragma unroll
      for (int i = 0; i < MF; ++i)
        acc[i][f] = __builtin_amdgcn_mfma_f32_16x16x32_f16(af[i], bf, acc[i][f], 0, 0, 0);
    }
    __syncthreads();
  }
  // epilogue: C/D layout col=lane&15, row=(lane>>4)*4+j
  #pragma unroll
  for (int i = 0; i < MF; ++i) {
    const int mbase = m0 + wm * (16 * MF) + i * 16 + lhi * 4;
    #pragma unroll
    for (int f = 0; f < 7; ++f) {
      int p = wn * 112 + f * 16 + l16;
      if (p < HW) {
        #pragma unroll
        for (int j = 0; j < 4; ++j)
          out[((size_t)n * M + (mbase + j)) * HW + p] = acc[i][f][j] + bias[mbase + j];
      }
    }
  }
}

// ---------------------------------------------------------------------------
// Persistent cooperative GRU: all 32 steps, 2 grid.sync per step.
// 512 blocks x 256 threads (exactly 2 blocks/CU).
// Block decode (phase1): kt = bx>>5 (0..7 z-conv, 8..15 r-conv),
// rowhalf = (bx>>4)&1, chain = bx&15.  Phase2 runs on bx<256 (the z-blocks,
// which hold z in registers -> no zbuf).
// fp32 math identical to the verified round-0 kernels.
// ---------------------------------------------------------------------------
__global__ __launch_bounds__(256, 2)
void gru_all(const float* __restrict__ wxb, const float* __restrict__ Uz,
             const float* __restrict__ Ur, const float* __restrict__ Uh,
             float* __restrict__ hbuf, float* __restrict__ rhbuf,
             float* __restrict__ assignb) {
  __shared__ float us1[8][KC][9];        // Uz or Ur slice (persistent)
  __shared__ float us2[8][KC][9];        // Uh slice (persistent, bx<256)
  __shared__ float hp[KC][10][16];       // padded h (or rh) halo, all 64 ch
  cg::grid_group grid = cg::this_grid();

  const int bx = blockIdx.x;
  const int tid = threadIdx.x;
  const int kt = bx >> 5;
  const int rowhalf = (bx >> 4) & 1;
  const int chain = bx & 15;
  const bool is_r = kt >= 8;
  const int k0 = (kt & 7) * 8;
  const int b = chain >> 1, dir = chain & 1;
  const int rowbase = rowhalf * 7;
  const bool p2act = bx < 256;

  const float* U1 = is_r ? Ur : Uz;
  for (int w = tid; w < 8 * KC * 9; w += 256) {
    int kl = w / (KC * 9);
    int rem = w - kl * (KC * 9);
    int ki = rem / 9, tap = rem - ki * 9;
    us1[kl][ki][tap] = U1[((size_t)(k0 + kl) * KC + ki) * 9 + tap];
  }
  if (p2act) {
    for (int w = tid; w < 8 * KC * 9; w += 256) {
      int kl = w / (KC * 9);
      int rem = w - kl * (KC * 9);
      int ki = rem / 9, tap = rem - ki * 9;
      us2[kl][ki][tap] = Uh[((size_t)(k0 + kl) * KC + ki) * 9 + tap];
    }
  }

  const int ko_l = tid >> 5;
  const int s = tid & 31;
  const int row_l = s >> 1;
  const int half = s & 1;
  const int x0 = half * 7;
  const bool active = row_l < 7;
  const int orow = rowbase + row_l;
  const int k = k0 + ko_l;
  float* hc = hbuf + (size_t)chain * KC * HW;
  float* rc = rhbuf + (size_t)chain * KC * HW;

  float zreg[7];

  for (int t = 0; t < T_STEPS; ++t) {
    const int tw = dir ? (T_STEPS - 1 - t) : t;
    const float* wt = wxb + (size_t)(b * T_STEPS + tw) * KC * HW;
    float wreg[7];
    if (active) {
      #pragma unroll
      for (int xi = 0; xi < 7; ++xi)
        wreg[xi] = wt[k * HW + orow * WIDTH + x0 + xi];
    }
    // ---- phase 1: conv(h, U1) ----
    __syncthreads();
    for (int w = tid; w < KC * 160; w += 256) {
      int ki = w / 160;
      int rem = w - ki * 160;
      int y = rem >> 4, xx = rem & 15;
      int srow = rowbase + y - 1, scol = xx - 1;
      float v = 0.0f;
      if (srow >= 0 && srow < WIDTH && scol >= 0 && scol < WIDTH)
        v = hc[ki * HW + srow * WIDTH + scol];
      hp[ki][y][xx] = v;
    }
    __syncthreads();
    if (active) {
      float acc[7] = {0, 0, 0, 0, 0, 0, 0};
      #pragma unroll 4
      for (int ki = 0; ki < KC; ++ki) {
        float u[9];
        #pragma unroll
        for (int tp = 0; tp < 9; ++tp) u[tp] = us1[ko_l][ki][tp];
        #pragma unroll
        for (int dy = 0; dy < 3; ++dy) {
          float hv[9];
          #pragma unroll
          for (int j = 0; j < 9; ++j) hv[j] = hp[ki][row_l + dy][x0 + j];
          #pragma unroll
          for (int xi = 0; xi < 7; ++xi)
            #pragma unroll
            for (int dx = 0; dx < 3; ++dx)
              acc[xi] = fmaf(u[dy * 3 + dx], hv[xi + dx], acc[xi]);
        }
      }
      #pragma unroll
      for (int xi = 0; xi < 7; ++xi) {
        int px = orow * WIDTH + x0 + xi;
        float sg = 1.0f / (1.0f + expf(-(acc[xi] + wreg[xi])));
        if (is_r) rc[k * HW + px] = sg * hc[k * HW + px];
        else      zreg[xi] = sg;
      }
    }
    grid.sync();
    // ---- phase 2: conv(rh, Uh), state update (bx<256 only) ----
    if (p2act) {
      for (int w = tid; w < KC * 160; w += 256) {
        int ki = w / 160;
        int rem = w - ki * 160;
        int y = rem >> 4, xx = rem & 15;
        int srow = rowbase + y - 1, scol = xx - 1;
        float v = 0.0f;
        if (srow >= 0 && srow < WIDTH && scol >= 0 && scol < WIDTH)
          v = rc[ki * HW + srow * WIDTH + scol];
        hp[ki][y][xx] = v;
      }
      __syncthreads();
      if (active) {
        float acc[7] = {0, 0, 0, 0, 0, 0, 0};
        #pragma unroll 4
        for (int ki = 0; ki < KC; ++ki) {
          float u[9];
          #pragma unroll
          for (int tp = 0; tp < 9; ++tp) u[tp] = us2[ko_l][ki][tp];
          #pragma unroll
          for (int dy = 0; dy < 3; ++dy) {
            float hv[9];
            #pragma unroll
            for (int j = 0; j < 9; ++j) hv[j] = hp[ki][row_l + dy][x0 + j];
            #pragma unroll
            for (int xi = 0; xi < 7; ++xi)
              #pragma unroll
              for (int dx = 0; dx < 3; ++dx)
                acc[xi] = fmaf(u[dy * 3 + dx], hv[xi + dx], acc[xi]);
          }
        }
        #pragma unroll
        for (int xi = 0; xi < 7; ++xi) {
          int px = orow * WIDTH + x0 + xi;
          float hh = tanhf(acc[xi] + wreg[xi]);
          float ho = hc[k * HW + px];
          float hn = (1.0f - zreg[xi]) * hh + zreg[xi] * ho;
          hc[k * HW + px] = hn;
          assignb[((size_t)(b * T_STEPS + tw) * KC + k) * HW + px] += hn;
        }
      }
    }
    grid.sync();
  }
}

// ---------------------------------------------------------------------------
// softmax over K=64 per (n,px) column, in place. grid 196 x 256 threads.
// ---------------------------------------------------------------------------
__global__ __launch_bounds__(256)
void softmax_kernel(float* __restrict__ a) {
  int idx = blockIdx.x * 256 + threadIdx.x;
  int n = idx / HW, px = idx - n * HW;
  float* col = a + (size_t)n * KC * HW + px;
  float v[KC];
  float mx = -3.4e38f;
  #pragma unroll
  for (int k = 0; k < KC; ++k) { v[k] = col[k * HW]; mx = fmaxf(mx, v[k]); }
  float ssum = 0.0f;
  #pragma unroll
  for (int k = 0; k < KC; ++k) { v[k] = expf(v[k] - mx); ssum += v[k]; }
  float inv = 1.0f / ssum;
  #pragma unroll
  for (int k = 0; k < KC; ++k) col[k * HW] = v[k] * inv;
}

__global__ __launch_bounds__(256)
void sreduce_kernel(const float* __restrict__ a, float* __restrict__ S) {
  __shared__ float red[256];
  const int k = blockIdx.x, b = blockIdx.y, tid = threadIdx.x;
  const float* base = a + ((size_t)b * T_STEPS * KC + k) * HW;
  float sum = 0.0f;
  for (int i = tid; i < T_STEPS * HW; i += 256) {
    int t = i / HW, p = i - t * HW;
    sum += base[(size_t)t * KC * HW + p];
  }
  red[tid] = sum; __syncthreads();
  for (int st = 128; st > 0; st >>= 1) {
    if (tid < st) red[tid] += red[tid + st];
    __syncthreads();
  }
  if (tid == 0) S[b * KC + k] = red[0];
}

__global__ __launch_bounds__(256)
void vlad_gemm_kernel(const float* __restrict__ a, const float* __restrict__ xr,
                      float* __restrict__ Gpart) {
  __shared__ float sA[16][68];
  __shared__ float sX[16][68];
  const int tid = threadIdx.x;
  const int tx = tid & 15, ty = tid >> 4;
  const int d0 = blockIdx.x * 64;
  const int tc = blockIdx.y;
  const int b  = blockIdx.z;
  const int lr = tid >> 2;
  const int pq = (tid & 3) * 4;
  float acc[4][4] = {};

  for (int tt = 0; tt < 8; ++tt) {
    int n = b * T_STEPS + tc * 8 + tt;
    const float* an = a + (size_t)n * KC * HW;
    const float* xn = xr + (size_t)n * DD * HW;
    for (int p0 = 0; p0 < HW; p0 += 16) {
      __syncthreads();
      #pragma unroll
      for (int j = 0; j < 4; ++j) {
        int p = p0 + pq + j;
        sA[pq + j][lr] = (p < HW) ? an[lr * HW + p] : 0.0f;
        sX[pq + j][lr] = (p < HW) ? xn[(d0 + lr) * HW + p] : 0.0f;
      }
      __syncthreads();
      #pragma unroll
      for (int pp = 0; pp < 16; ++pp) {
        float4 av = *reinterpret_cast<const float4*>(&sA[pp][ty * 4]);
        float4 xv = *reinterpret_cast<const float4*>(&sX[pp][tx * 4]);
        float aa[4] = {av.x, av.y, av.z, av.w};
        float xx[4] = {xv.x, xv.y, xv.z, xv.w};
        #pragma unroll
        for (int i = 0; i < 4; ++i)
          #pragma unroll
          for (int j = 0; j < 4; ++j)
            acc[i][j] += aa[i] * xx[j];
      }
    }
  }
  float* gp = Gpart + ((size_t)(tc * NB + b) * KC) * DD;
  #pragma unroll
  for (int i = 0; i < 4; ++i)
    #pragma unroll
    for (int j = 0; j < 4; ++j)
      gp[(ty * 4 + i) * DD + d0 + tx * 4 + j] = acc[i][j];
}

__global__ __launch_bounds__(256)
void finalize1_kernel(const float* __restrict__ Gpart, const float* __restrict__ S,
                      const float* __restrict__ centers, float* __restrict__ out,
                      float* __restrict__ bsum) {
  __shared__ float red[256];
  const int k = blockIdx.x, b = blockIdx.y, tid = threadIdx.x;
  const float sv = S[b * KC + k];
  float vals[2];
  float ss = 0.0f;
  #pragma unroll
  for (int r = 0; r < 2; ++r) {
    int d = tid + r * 256;
    float g = 0.0f;
    #pragma unroll
    for (int tc = 0; tc < 4; ++tc)
      g += Gpart[((size_t)(tc * NB + b) * KC + k) * DD + d];
    float v = g - sv * centers[k * DD + d];
    vals[r] = v; ss += v * v;
  }
  red[tid] = ss; __syncthreads();
  for (int st = 128; st > 0; st >>= 1) {
    if (tid < st) red[tid] += red[tid + st];
    __syncthreads();
  }
  float tot = red[0];
  float inv = 1.0f / fmaxf(sqrtf(tot), 1e-12f);
  #pragma unroll
  for (int r = 0; r < 2; ++r) {
    int d = tid + r * 256;
    out[(size_t)b * KC * DD + k * DD + d] = vals[r] * inv;
  }
  if (tid == 0) atomicAdd(&bsum[b], tot * inv * inv);
}

__global__ __launch_bounds__(256)
void finalize2_kernel(float* __restrict__ out, const float* __restrict__ bsum) {
  int idx = blockIdx.x * 256 + threadIdx.x;
  int b = idx >> 15;
  out[idx] = out[idx] / fmaxf(sqrtf(bsum[b]), 1e-12f);
}

// ---------------------------------------------------------------------------
extern "C" void kernel_launch(void* const* d_in, const int* in_sizes, int n_in,
                              void* d_out, int out_size, void* d_ws, size_t ws_size,
                              hipStream_t stream) {
  const float* x       = (const float*)d_in[0];
  const float* redu_w  = (const float*)d_in[1];
  const float* redu_b  = (const float*)d_in[2];
  const float* share_w = (const float*)d_in[3];
  const float* share_b = (const float*)d_in[4];
  const float* Uz      = (const float*)d_in[5];
  const float* Ur      = (const float*)d_in[6];
  const float* Uh      = (const float*)d_in[7];
  const float* centers = (const float*)d_in[8];
  float* out = (float*)d_out;

  float* xr     = (float*)d_ws;                       // 256*512*196
  float* wxb    = xr     + (size_t)NFR * DD * HW;     // 256*64*196
  float* assignb= wxb    + (size_t)NFR * KC * HW;     // 256*64*196
  float* hbuf   = assignb+ (size_t)NFR * KC * HW;     // 16*64*196
  float* rhbuf  = hbuf   + (size_t)16 * KC * HW;      // 16*64*196
  float* Gpart  = rhbuf  + (size_t)16 * KC * HW;      // 4*8*64*512
  float* S      = Gpart  + (size_t)4 * NB * KC * DD;  // 512
  float* bsum   = S      + 512;                       // 8

  hipMemsetAsync(assignb, 0, (size_t)NFR * KC * HW * sizeof(float), stream);
  hipMemsetAsync(hbuf, 0, (size_t)16 * KC * HW * sizeof(float), stream);
  hipMemsetAsync(bsum, 0, NB * sizeof(float), stream);

  // stage A: 1024 -> 512 reduction conv (fp16 MFMA), 4 m-tiles x 256 frames
  conv1x1_mfma<128><<<dim3(1024), 256, 0, stream>>>(x, redu_w, redu_b, xr, CIN, DD);
  // stage B: 512 -> 64 share conv (fp16 MFMA), 1 m-tile x 256 frames
  conv1x1_mfma<64><<<dim3(256), 256, 0, stream>>>(xr, share_w, share_b, wxb, DD, KC);

  // GRU recurrence: single persistent cooperative kernel
  {
    void* args[7];
    args[0] = (void*)&wxb;
    args[1] = (void*)&Uz;
    args[2] = (void*)&Ur;
    args[3] = (void*)&Uh;
    args[4] = (void*)&hbuf;
    args[5] = (void*)&rhbuf;
    args[6] = (void*)&assignb;
    hipLaunchCooperativeKernel((void*)gru_all, dim3(512), dim3(256), args, 0, stream);
  }

  softmax_kernel<<<dim3(196), 256, 0, stream>>>(assignb);
  sreduce_kernel<<<dim3(64, 8), 256, 0, stream>>>(assignb, S);
  vlad_gemm_kernel<<<dim3(8, 4, 8), 256, 0, stream>>>(assignb, xr, Gpart);
  finalize1_kernel<<<dim3(64, 8), 256, 0, stream>>>(Gpart, S, centers, out, bsum);
  finalize2_kernel<<<dim3(1024), 256, 0, stream>>>(out, bsum);
}

// Round 3
// 2392.787 us; speedup vs baseline: 3.4336x; 3.4336x over previous
//
#include <hip/hip_runtime.h>

#define HW 196
#define WIDTH 14
#define T_STEPS 32
#define KC 64      // centers / GRU channels
#define DD 512     // reduced dim
#define CIN 1024
#define NFR 256    // B*T
#define NB 8       // videos

using f16x8 = __attribute__((ext_vector_type(8))) _Float16;
using f16x4 = __attribute__((ext_vector_type(4))) _Float16;
using f32x4 = __attribute__((ext_vector_type(4))) float;

// ---------------------------------------------------------------------------
// fp16 MFMA 1x1 conv: out[n][m][p] = bias[m] + sum_c W[m][c]*in[n][c][p]
// (validated in round 1: absmax 6.1e-5 end-to-end)
// ---------------------------------------------------------------------------
template<int BM>
__global__ __launch_bounds__(256)
void conv1x1_mfma(const float* __restrict__ in, const float* __restrict__ W,
                  const float* __restrict__ bias, float* __restrict__ out,
                  int C, int M) {
  constexpr int MF = BM / 32;           // m-frags per wave
  __shared__ _Float16 sA[BM][40];       // [m][k]
  __shared__ _Float16 sX[224][40];      // [p][k] transposed X tile
  const int tid = threadIdx.x;
  const int lane = tid & 63;
  const int wv = tid >> 6;
  const int wm = wv >> 1, wn = wv & 1;
  const int l16 = lane & 15, lhi = lane >> 4;

  int n, mt;
  if (BM == 128) {
    int xcd = blockIdx.x & 7;
    int idx = blockIdx.x >> 3;
    n = xcd * 32 + (idx >> 2);
    mt = idx & 3;
  } else {
    n = blockIdx.x; mt = 0;
  }
  const int m0 = mt * BM;
  const float* inN = in + (size_t)n * C * HW;

  f32x4 acc[MF][7];
  #pragma unroll
  for (int i = 0; i < MF; ++i)
    #pragma unroll
    for (int f = 0; f < 7; ++f) acc[i][f] = {0.f, 0.f, 0.f, 0.f};

  for (int c0 = 0; c0 < C; c0 += 32) {
    for (int e = tid * 2; e < BM * 32; e += 512) {
      int r = e >> 5, kk = e & 31;
      float2 w2 = *reinterpret_cast<const float2*>(&W[(size_t)(m0 + r) * C + c0 + kk]);
      sA[r][kk] = (_Float16)w2.x;
      sA[r][kk + 1] = (_Float16)w2.y;
    }
    if (tid < 224) {
      #pragma unroll
      for (int g = 0; g < 4; ++g) {
        f16x8 v;
        #pragma unroll
        for (int j = 0; j < 8; ++j) {
          float xv = (tid < HW) ? inN[(size_t)(c0 + g * 8 + j) * HW + tid] : 0.0f;
          v[j] = (_Float16)xv;
        }
        *reinterpret_cast<f16x8*>(&sX[tid][g * 8]) = v;
      }
    }
    __syncthreads();
    f16x8 af[MF];
    #pragma unroll
    for (int i = 0; i < MF; ++i)
      af[i] = *reinterpret_cast<const f16x8*>(&sA[wm * (16 * MF) + i * 16 + l16][lhi * 8]);
    #pragma unroll
    for (int f = 0; f < 7; ++f) {
      f16x8 bf = *reinterpret_cast<const f16x8*>(&sX[wn * 112 + f * 16 + l16][lhi * 8]);
      #pragma unroll
      for (int i = 0; i < MF; ++i)
        acc[i][f] = __builtin_amdgcn_mfma_f32_16x16x32_f16(af[i], bf, acc[i][f], 0, 0, 0);
    }
    __syncthreads();
  }
  #pragma unroll
  for (int i = 0; i < MF; ++i) {
    const int mbase = m0 + wm * (16 * MF) + i * 16 + lhi * 4;
    #pragma unroll
    for (int f = 0; f < 7; ++f) {
      int p = wn * 112 + f * 16 + l16;
      if (p < HW) {
        #pragma unroll
        for (int j = 0; j < 4; ++j)
          out[((size_t)n * M + (mbase + j)) * HW + p] = acc[i][f][j] + bias[mbase + j];
      }
    }
  }
}

// ---------------------------------------------------------------------------
// GRU via MFMA implicit GEMM. One block (4 waves) per chain; h lives in LDS
// for all 32 steps (fp16 swizzled for MFMA B-operand + fp32 for recurrence).
// U weights live in registers as pre-formatted A-fragments.
// k index = tap*64 + ki; k-tile kt: tap = kt>>1, ki0 = (kt&1)*32.
// LDS fp16 pixel buffers: [pixel-slot][64ch], 128B/slot, byte swizzle
// chbyte ^= (pp&7)<<4  (T2) -> conflict-free ds_read_b128 / 8B writes.
// ---------------------------------------------------------------------------
__global__ __launch_bounds__(256, 1)
void gru_mfma(const float* __restrict__ wxb, const float* __restrict__ Uz,
              const float* __restrict__ Ur, const float* __restrict__ Uh,
              _Float16* __restrict__ a_f, _Float16* __restrict__ a_b) {
  __shared__ __align__(16) _Float16 hpad[256 * 64];   // padded 16x16 pixels, 32KB
  __shared__ __align__(16) _Float16 rhpad[256 * 64];  // 32KB
  __shared__ __align__(16) _Float16 zbuf[208 * 64];   // [pixel][ch], 26.6KB
  __shared__ float h32[KC * HW];                      // fp32 h, 50KB

  const int tid = threadIdx.x;
  const int lane = tid & 63;
  const int w = tid >> 6;          // wave 0..3
  const int l16 = lane & 15, lhi = lane >> 4;
  const int chain = blockIdx.x;
  const int b = chain >> 1, dir = chain & 1;
  const int wsel = w & 1;
  const int pair = w >> 1;

  // zero persistent LDS state (h = 0, halo borders stay 0 forever)
  for (int i = tid; i < 256 * 64; i += 256) { hpad[i] = (_Float16)0.f; rhpad[i] = (_Float16)0.f; }
  for (int i = tid; i < KC * HW; i += 256) h32[i] = 0.0f;

  // ---- load A-fragments (U weights) into registers ----
  // phase1: waves 0,1 -> U_z rows {0-31},{32-63}; waves 2,3 -> U_r same rows.
  // phase2: wave pair 0 (w 0,1) -> U_h rows 0-31; pair 1 -> rows 32-63.
  const float* U1 = (w >= 2) ? Ur : Uz;
  f16x8 af1[2][18];
  f16x8 af2[2][18];
  #pragma unroll
  for (int mi = 0; mi < 2; ++mi) {
    const int ko1 = (wsel * 2 + mi) * 16 + l16;
    const int ko2 = (pair * 2 + mi) * 16 + l16;
    #pragma unroll
    for (int kt = 0; kt < 18; ++kt) {
      const int tap = kt >> 1;
      const int kib = (kt & 1) * 32 + lhi * 8;
      f16x8 v1, v2;
      #pragma unroll
      for (int j = 0; j < 8; ++j) {
        v1[j] = (_Float16)U1[(size_t)ko1 * 576 + (kib + j) * 9 + tap];
        v2[j] = (_Float16)Uh[(size_t)ko2 * 576 + (kib + j) * 9 + tap];
      }
      af1[mi][kt] = v1; af2[mi][kt] = v2;
    }
  }
  __syncthreads();

  _Float16* adest = dir ? a_b : a_f;
  const char* hpadB = reinterpret_cast<const char*>(hpad);
  const char* rhpadB = reinterpret_cast<const char*>(rhpad);

  for (int t = 0; t < T_STEPS; ++t) {
    const int tw = dir ? (T_STEPS - 1 - t) : t;
    const float* wt = wxb + (size_t)(b * T_STEPS + tw) * KC * HW;

    // ================= phase 1: z (waves 0,1) / r (waves 2,3) =================
    for (int nt = 0; nt < 13; ++nt) {
      const int p = nt * 16 + l16;
      const int pc = (p < HW) ? p : (HW - 1);
      const bool valid = p < HW;
      const int py = pc / 14, px = pc - py * 14;
      const int base0 = py * 16 + px;       // padded idx of tap(0,0) source

      float wtv[2][4];
      #pragma unroll
      for (int mi = 0; mi < 2; ++mi)
        #pragma unroll
        for (int jj = 0; jj < 4; ++jj)
          wtv[mi][jj] = wt[((wsel * 2 + mi) * 16 + lhi * 4 + jj) * HW + pc];

      f32x4 acc[2];
      acc[0] = {0.f, 0.f, 0.f, 0.f};
      acc[1] = {0.f, 0.f, 0.f, 0.f};
      #pragma unroll
      for (int kt = 0; kt < 18; ++kt) {
        const int tap = kt >> 1, dy = tap / 3, dx = tap - dy * 3;
        const int pp = base0 + dy * 16 + dx;
        const int chb = (kt & 1) * 64 + lhi * 16;
        const f16x8 bf = *reinterpret_cast<const f16x8*>(
            hpadB + pp * 128 + (chb ^ ((pp & 7) << 4)));
        acc[0] = __builtin_amdgcn_mfma_f32_16x16x32_f16(af1[0][kt], bf, acc[0], 0, 0, 0);
        acc[1] = __builtin_amdgcn_mfma_f32_16x16x32_f16(af1[1][kt], bf, acc[1], 0, 0, 0);
      }
      if (valid) {
        if (w < 2) {
          // z = sigmoid(pre) -> zbuf (fp16, swizzled [pixel][ch])
          #pragma unroll
          for (int mi = 0; mi < 2; ++mi) {
            const int ch0 = (wsel * 2 + mi) * 16 + lhi * 4;
            f16x4 zw;
            #pragma unroll
            for (int jj = 0; jj < 4; ++jj) {
              float pre = acc[mi][jj] + wtv[mi][jj];
              zw[jj] = (_Float16)(1.0f / (1.0f + expf(-pre)));
            }
            *reinterpret_cast<f16x4*>(reinterpret_cast<char*>(zbuf) +
                p * 128 + ((ch0 * 2) ^ ((p & 7) << 4))) = zw;
          }
        } else {
          // rh = sigmoid(pre) * h32 -> rhpad (fp16, padded+swizzled)
          const int ppw = base0 + 17;
          #pragma unroll
          for (int mi = 0; mi < 2; ++mi) {
            const int ch0 = (wsel * 2 + mi) * 16 + lhi * 4;
            f16x4 rhw;
            #pragma unroll
            for (int jj = 0; jj < 4; ++jj) {
              float pre = acc[mi][jj] + wtv[mi][jj];
              float r = 1.0f / (1.0f + expf(-pre));
              rhw[jj] = (_Float16)(r * h32[(ch0 + jj) * HW + pc]);
            }
            *reinterpret_cast<f16x4*>(reinterpret_cast<char*>(rhpad) +
                ppw * 128 + ((ch0 * 2) ^ ((ppw & 7) << 4))) = rhw;
          }
        }
      }
    }
    __syncthreads();

    // ================= phase 2: hh = tanh(wt + conv(rh,Uh)); update h ========
    // wave pair `pair` owns ch [pair*32, pair*32+32); member wsel takes
    // nt = wsel, wsel+2, ... (nt=13 is a harmless dummy tile).
    for (int i = 0; i < 7; ++i) {
      const int nt = wsel + 2 * i;
      const int p = nt * 16 + l16;
      const int pc = (p < HW) ? p : (HW - 1);
      const bool valid = p < HW;
      const int py = pc / 14, px = pc - py * 14;
      const int base0 = py * 16 + px;

      float wtv[2][4];
      #pragma unroll
      for (int mi = 0; mi < 2; ++mi)
        #pragma unroll
        for (int jj = 0; jj < 4; ++jj)
          wtv[mi][jj] = wt[((pair * 2 + mi) * 16 + lhi * 4 + jj) * HW + pc];

      f32x4 acc[2];
      acc[0] = {0.f, 0.f, 0.f, 0.f};
      acc[1] = {0.f, 0.f, 0.f, 0.f};
      #pragma unroll
      for (int kt = 0; kt < 18; ++kt) {
        const int tap = kt >> 1, dy = tap / 3, dx = tap - dy * 3;
        const int pp = base0 + dy * 16 + dx;
        const int chb = (kt & 1) * 64 + lhi * 16;
        const f16x8 bf = *reinterpret_cast<const f16x8*>(
            rhpadB + pp * 128 + (chb ^ ((pp & 7) << 4)));
        acc[0] = __builtin_amdgcn_mfma_f32_16x16x32_f16(af2[0][kt], bf, acc[0], 0, 0, 0);
        acc[1] = __builtin_amdgcn_mfma_f32_16x16x32_f16(af2[1][kt], bf, acc[1], 0, 0, 0);
      }
      if (valid) {
        const int ppw = base0 + 17;
        #pragma unroll
        for (int mi = 0; mi < 2; ++mi) {
          const int ch0 = (pair * 2 + mi) * 16 + lhi * 4;
          const f16x4 zv = *reinterpret_cast<const f16x4*>(
              reinterpret_cast<const char*>(zbuf) + p * 128 + ((ch0 * 2) ^ ((p & 7) << 4)));
          f16x4 hw;
          #pragma unroll
          for (int jj = 0; jj < 4; ++jj) {
            float hh = tanhf(acc[mi][jj] + wtv[mi][jj]);
            float z = (float)zv[jj];
            float ho = h32[(ch0 + jj) * HW + pc];
            float hn = (1.0f - z) * hh + z * ho;
            h32[(ch0 + jj) * HW + pc] = hn;
            hw[jj] = (_Float16)hn;
            adest[((size_t)(b * T_STEPS + tw) * KC + ch0 + jj) * HW + pc] = (_Float16)hn;
          }
          *reinterpret_cast<f16x4*>(reinterpret_cast<char*>(hpad) +
              ppw * 128 + ((ch0 * 2) ^ ((ppw & 7) << 4))) = hw;
        }
      }
    }
    __syncthreads();
  }
}

// ---------------------------------------------------------------------------
// softmax over K=64 per (n,px): logits = a_f + a_b (fp16), output fp32.
// ---------------------------------------------------------------------------
__global__ __launch_bounds__(256)
void softmax_kernel(const _Float16* __restrict__ af, const _Float16* __restrict__ ab,
                    float* __restrict__ out) {
  int idx = blockIdx.x * 256 + threadIdx.x;
  int n = idx / HW, px = idx - n * HW;
  const _Float16* cf = af + (size_t)n * KC * HW + px;
  const _Float16* cb = ab + (size_t)n * KC * HW + px;
  float* co = out + (size_t)n * KC * HW + px;
  float v[KC];
  float mx = -3.4e38f;
  #pragma unroll
  for (int k = 0; k < KC; ++k) {
    v[k] = (float)cf[k * HW] + (float)cb[k * HW];
    mx = fmaxf(mx, v[k]);
  }
  float ssum = 0.0f;
  #pragma unroll
  for (int k = 0; k < KC; ++k) { v[k] = expf(v[k] - mx); ssum += v[k]; }
  float inv = 1.0f / ssum;
  #pragma unroll
  for (int k = 0; k < KC; ++k) co[k * HW] = v[k] * inv;
}

__global__ __launch_bounds__(256)
void sreduce_kernel(const float* __restrict__ a, float* __restrict__ S) {
  __shared__ float red[256];
  const int k = blockIdx.x, b = blockIdx.y, tid = threadIdx.x;
  const float* base = a + ((size_t)b * T_STEPS * KC + k) * HW;
  float sum = 0.0f;
  for (int i = tid; i < T_STEPS * HW; i += 256) {
    int t = i / HW, p = i - t * HW;
    sum += base[(size_t)t * KC * HW + p];
  }
  red[tid] = sum; __syncthreads();
  for (int st = 128; st > 0; st >>= 1) {
    if (tid < st) red[tid] += red[tid + st];
    __syncthreads();
  }
  if (tid == 0) S[b * KC + k] = red[0];
}

__global__ __launch_bounds__(256)
void vlad_gemm_kernel(const float* __restrict__ a, const float* __restrict__ xr,
                      float* __restrict__ Gpart) {
  __shared__ float sA[16][68];
  __shared__ float sX[16][68];
  const int tid = threadIdx.x;
  const int tx = tid & 15, ty = tid >> 4;
  const int d0 = blockIdx.x * 64;
  const int tc = blockIdx.y;
  const int b  = blockIdx.z;
  const int lr = tid >> 2;
  const int pq = (tid & 3) * 4;
  float acc[4][4] = {};

  for (int tt = 0; tt < 8; ++tt) {
    int n = b * T_STEPS + tc * 8 + tt;
    const float* an = a + (size_t)n * KC * HW;
    const float* xn = xr + (size_t)n * DD * HW;
    for (int p0 = 0; p0 < HW; p0 += 16) {
      __syncthreads();
      #pragma unroll
      for (int j = 0; j < 4; ++j) {
        int p = p0 + pq + j;
        sA[pq + j][lr] = (p < HW) ? an[lr * HW + p] : 0.0f;
        sX[pq + j][lr] = (p < HW) ? xn[(d0 + lr) * HW + p] : 0.0f;
      }
      __syncthreads();
      #pragma unroll
      for (int pp = 0; pp < 16; ++pp) {
        float4 av = *reinterpret_cast<const float4*>(&sA[pp][ty * 4]);
        float4 xv = *reinterpret_cast<const float4*>(&sX[pp][tx * 4]);
        float aa[4] = {av.x, av.y, av.z, av.w};
        float xx[4] = {xv.x, xv.y, xv.z, xv.w};
        #pragma unroll
        for (int i = 0; i < 4; ++i)
          #pragma unroll
          for (int j = 0; j < 4; ++j)
            acc[i][j] += aa[i] * xx[j];
      }
    }
  }
  float* gp = Gpart + ((size_t)(tc * NB + b) * KC) * DD;
  #pragma unroll
  for (int i = 0; i < 4; ++i)
    #pragma unroll
    for (int j = 0; j < 4; ++j)
      gp[(ty * 4 + i) * DD + d0 + tx * 4 + j] = acc[i][j];
}

__global__ __launch_bounds__(256)
void finalize1_kernel(const float* __restrict__ Gpart, const float* __restrict__ S,
                      const float* __restrict__ centers, float* __restrict__ out,
                      float* __restrict__ bsum) {
  __shared__ float red[256];
  const int k = blockIdx.x, b = blockIdx.y, tid = threadIdx.x;
  const float sv = S[b * KC + k];
  float vals[2];
  float ss = 0.0f;
  #pragma unroll
  for (int r = 0; r < 2; ++r) {
    int d = tid + r * 256;
    float g = 0.0f;
    #pragma unroll
    for (int tc = 0; tc < 4; ++tc)
      g += Gpart[((size_t)(tc * NB + b) * KC + k) * DD + d];
    float v = g - sv * centers[k * DD + d];
    vals[r] = v; ss += v * v;
  }
  red[tid] = ss; __syncthreads();
  for (int st = 128; st > 0; st >>= 1) {
    if (tid < st) red[tid] += red[tid + st];
    __syncthreads();
  }
  float tot = red[0];
  float inv = 1.0f / fmaxf(sqrtf(tot), 1e-12f);
  #pragma unroll
  for (int r = 0; r < 2; ++r) {
    int d = tid + r * 256;
    out[(size_t)b * KC * DD + k * DD + d] = vals[r] * inv;
  }
  if (tid == 0) atomicAdd(&bsum[b], tot * inv * inv);
}

__global__ __launch_bounds__(256)
void finalize2_kernel(float* __restrict__ out, const float* __restrict__ bsum) {
  int idx = blockIdx.x * 256 + threadIdx.x;
  int b = idx >> 15;
  out[idx] = out[idx] / fmaxf(sqrtf(bsum[b]), 1e-12f);
}

// ---------------------------------------------------------------------------
extern "C" void kernel_launch(void* const* d_in, const int* in_sizes, int n_in,
                              void* d_out, int out_size, void* d_ws, size_t ws_size,
                              hipStream_t stream) {
  const float* x       = (const float*)d_in[0];
  const float* redu_w  = (const float*)d_in[1];
  const float* redu_b  = (const float*)d_in[2];
  const float* share_w = (const float*)d_in[3];
  const float* share_b = (const float*)d_in[4];
  const float* Uz      = (const float*)d_in[5];
  const float* Ur      = (const float*)d_in[6];
  const float* Uh      = (const float*)d_in[7];
  const float* centers = (const float*)d_in[8];
  float* out = (float*)d_out;

  float* xr = (float*)d_ws;                                  // 256*512*196 f32
  float* wxb = xr + (size_t)NFR * DD * HW;                   // 256*64*196 f32 (later: combined assign)
  _Float16* a_f = (_Float16*)(wxb + (size_t)NFR * KC * HW);  // 256*64*196 f16
  _Float16* a_b = a_f + (size_t)NFR * KC * HW;               // 256*64*196 f16
  float* Gpart = (float*)(a_b + (size_t)NFR * KC * HW);      // 4*8*64*512 f32
  float* S = Gpart + (size_t)4 * NB * KC * DD;               // 512
  float* bsum = S + 512;                                     // 8
  float* assignc = wxb;  // combined softmax output overlays wxb (dead after GRU)

  hipMemsetAsync(bsum, 0, NB * sizeof(float), stream);

  // stage A: 1024 -> 512 reduction conv (fp16 MFMA)
  conv1x1_mfma<128><<<dim3(1024), 256, 0, stream>>>(x, redu_w, redu_b, xr, CIN, DD);
  // stage B: 512 -> 64 share conv (fp16 MFMA)
  conv1x1_mfma<64><<<dim3(256), 256, 0, stream>>>(xr, share_w, share_b, wxb, DD, KC);

  // GRU: 16 independent chain blocks, MFMA implicit GEMM, LDS-resident state
  gru_mfma<<<dim3(16), 256, 0, stream>>>(wxb, Uz, Ur, Uh, a_f, a_b);

  softmax_kernel<<<dim3(196), 256, 0, stream>>>(a_f, a_b, assignc);
  sreduce_kernel<<<dim3(64, 8), 256, 0, stream>>>(assignc, S);
  vlad_gemm_kernel<<<dim3(8, 4, 8), 256, 0, stream>>>(assignc, xr, Gpart);
  finalize1_kernel<<<dim3(64, 8), 256, 0, stream>>>(Gpart, S, centers, out, bsum);
  finalize2_kernel<<<dim3(1024), 256, 0, stream>>>(out, bsum);
}

// Round 4
// 2109.184 us; speedup vs baseline: 3.8953x; 1.1345x over previous
//
#include <hip/hip_runtime.h>

#define HW 196
#define WIDTH 14
#define T_STEPS 32
#define KC 64      // centers / GRU channels
#define DD 512     // reduced dim
#define CIN 1024
#define NFR 256    // B*T
#define NB 8       // videos

using f16x8 = __attribute__((ext_vector_type(8))) _Float16;
using f16x4 = __attribute__((ext_vector_type(4))) _Float16;
using f32x4 = __attribute__((ext_vector_type(4))) float;

// ---------------------------------------------------------------------------
// fp16 MFMA 1x1 conv: out[n][m][p] = bias[m] + sum_c W[m][c]*in[n][c][p]
// (validated rounds 1-2)
// ---------------------------------------------------------------------------
template<int BM>
__global__ __launch_bounds__(256)
void conv1x1_mfma(const float* __restrict__ in, const float* __restrict__ W,
                  const float* __restrict__ bias, float* __restrict__ out,
                  int C, int M) {
  constexpr int MF = BM / 32;           // m-frags per wave
  __shared__ _Float16 sA[BM][40];       // [m][k]
  __shared__ _Float16 sX[224][40];      // [p][k] transposed X tile
  const int tid = threadIdx.x;
  const int lane = tid & 63;
  const int wv = tid >> 6;
  const int wm = wv >> 1, wn = wv & 1;
  const int l16 = lane & 15, lhi = lane >> 4;

  int n, mt;
  if (BM == 128) {
    int xcd = blockIdx.x & 7;
    int idx = blockIdx.x >> 3;
    n = xcd * 32 + (idx >> 2);
    mt = idx & 3;
  } else {
    n = blockIdx.x; mt = 0;
  }
  const int m0 = mt * BM;
  const float* inN = in + (size_t)n * C * HW;

  f32x4 acc[MF][7];
  #pragma unroll
  for (int i = 0; i < MF; ++i)
    #pragma unroll
    for (int f = 0; f < 7; ++f) acc[i][f] = {0.f, 0.f, 0.f, 0.f};

  for (int c0 = 0; c0 < C; c0 += 32) {
    for (int e = tid * 2; e < BM * 32; e += 512) {
      int r = e >> 5, kk = e & 31;
      float2 w2 = *reinterpret_cast<const float2*>(&W[(size_t)(m0 + r) * C + c0 + kk]);
      sA[r][kk] = (_Float16)w2.x;
      sA[r][kk + 1] = (_Float16)w2.y;
    }
    if (tid < 224) {
      #pragma unroll
      for (int g = 0; g < 4; ++g) {
        f16x8 v;
        #pragma unroll
        for (int j = 0; j < 8; ++j) {
          float xv = (tid < HW) ? inN[(size_t)(c0 + g * 8 + j) * HW + tid] : 0.0f;
          v[j] = (_Float16)xv;
        }
        *reinterpret_cast<f16x8*>(&sX[tid][g * 8]) = v;
      }
    }
    __syncthreads();
    f16x8 af[MF];
    #pragma unroll
    for (int i = 0; i < MF; ++i)
      af[i] = *reinterpret_cast<const f16x8*>(&sA[wm * (16 * MF) + i * 16 + l16][lhi * 8]);
    #pragma unroll
    for (int f = 0; f < 7; ++f) {
      f16x8 bf = *reinterpret_cast<const f16x8*>(&sX[wn * 112 + f * 16 + l16][lhi * 8]);
      #pragma unroll
      for (int i = 0; i < MF; ++i)
        acc[i][f] = __builtin_amdgcn_mfma_f32_16x16x32_f16(af[i], bf, acc[i][f], 0, 0, 0);
    }
    __syncthreads();
  }
  #pragma unroll
  for (int i = 0; i < MF; ++i) {
    const int mbase = m0 + wm * (16 * MF) + i * 16 + lhi * 4;
    #pragma unroll
    for (int f = 0; f < 7; ++f) {
      int p = wn * 112 + f * 16 + l16;
      if (p < HW) {
        #pragma unroll
        for (int j = 0; j < 4; ++j)
          out[((size_t)n * M + (mbase + j)) * HW + p] = acc[i][f][j] + bias[mbase + j];
      }
    }
  }
}

// ---------------------------------------------------------------------------
// Pre-format U weights into MFMA A-fragments (fp16, 16B per lane per frag).
// frag f < 144: phase1, f = pair*36 + mi*18 + kt, pair<2 -> Uz, else Ur,
//   out-ch = (pair&1)*32 + mi*16 + l16.
// frag f >= 144: phase2, g = f-144 = pair2*36 + mi*18 + kt, U_h,
//   out-ch = pair2*32 + mi*16 + l16.
// k = (kt&1)*32 + (lane>>4)*8 + j, tap = kt>>1.
// ---------------------------------------------------------------------------
__global__ __launch_bounds__(64)
void format_u(const float* __restrict__ Uz, const float* __restrict__ Ur,
              const float* __restrict__ Uh, _Float16* __restrict__ ufmt) {
  const int f = blockIdx.x;        // 0..215
  const int lane = threadIdx.x;
  const int l16 = lane & 15;
  const float* U;
  int ch, kt;
  if (f < 144) {
    int pair = f / 36, rem = f - pair * 36;
    int mi = rem / 18; kt = rem - mi * 18;
    U = (pair < 2) ? Uz : Ur;
    ch = (pair & 1) * 32 + mi * 16 + l16;
  } else {
    int g = f - 144;
    int pair = g / 36, rem = g - pair * 36;
    int mi = rem / 18; kt = rem - mi * 18;
    U = Uh;
    ch = pair * 32 + mi * 16 + l16;
  }
  const int tap = kt >> 1;
  const int k0 = (kt & 1) * 32 + (lane >> 4) * 8;
  f16x8 v;
  #pragma unroll
  for (int j = 0; j < 8; ++j)
    v[j] = (_Float16)U[(size_t)ch * 576 + (k0 + j) * 9 + tap];
  *reinterpret_cast<f16x8*>(ufmt + (size_t)f * 512 + lane * 8) = v;
}

// ---------------------------------------------------------------------------
// GRU via MFMA implicit GEMM, 16 waves per block (1024 thr), one block per
// chain. U A-fragments streamed from L2 (ufmt) instead of registers.
// Phase1: 52 jobs = (nt 13) x (pair 4) [pair<2: z, else r], job j = w + 16i.
// Phase2: 26 jobs = (nt 13) x (pair2 2).
// LDS pixel buffers swizzled (byte ^= (slot&7)<<4) -> conflict-free b128.
// ---------------------------------------------------------------------------
__global__ __launch_bounds__(1024)
void gru_mfma16(const float* __restrict__ wxb, const _Float16* __restrict__ ufmt,
                _Float16* __restrict__ a_f, _Float16* __restrict__ a_b) {
  __shared__ __align__(16) _Float16 hpad[256 * 64];   // 32KB padded h
  __shared__ __align__(16) _Float16 rhpad[256 * 64];  // 32KB padded r*h
  __shared__ __align__(16) _Float16 zbuf[208 * 64];   // 26.6KB z
  __shared__ float h32[KC * HW];                      // 50KB fp32 h

  const int tid = threadIdx.x;
  const int lane = tid & 63;
  const int w = tid >> 6;          // wave 0..15
  const int l16 = lane & 15, lhi = lane >> 4;
  const int chain = blockIdx.x;
  const int b = chain >> 1, dir = chain & 1;

  for (int i = tid; i < 256 * 64; i += 1024) { hpad[i] = (_Float16)0.f; rhpad[i] = (_Float16)0.f; }
  for (int i = tid; i < KC * HW; i += 1024) h32[i] = 0.0f;
  __syncthreads();

  _Float16* adest = dir ? a_b : a_f;
  const char* hpadB = reinterpret_cast<const char*>(hpad);
  const char* rhpadB = reinterpret_cast<const char*>(rhpad);

  for (int t = 0; t < T_STEPS; ++t) {
    const int tw = dir ? (T_STEPS - 1 - t) : t;
    const float* wt = wxb + (size_t)(b * T_STEPS + tw) * KC * HW;

    // ================= phase 1: z (pair 0,1) / r (pair 2,3) =================
    for (int j = w; j < 52; j += 16) {
      const int pair = j & 3, nt = j >> 2;
      const bool isr = pair >= 2;
      const int chbase = (pair & 1) * 32;
      const int p = nt * 16 + l16;
      const int pc = (p < HW) ? p : (HW - 1);
      const bool valid = p < HW;
      const int py = pc / 14, px = pc - py * 14;
      const int base0 = py * 16 + px;

      float wtv[2][4];
      #pragma unroll
      for (int mi = 0; mi < 2; ++mi)
        #pragma unroll
        for (int jj = 0; jj < 4; ++jj)
          wtv[mi][jj] = wt[(chbase + mi * 16 + lhi * 4 + jj) * HW + pc];

      const _Float16* af0 = ufmt + ((size_t)pair * 36) * 512 + lane * 8;
      f32x4 acc0 = {0.f, 0.f, 0.f, 0.f};
      f32x4 acc1 = {0.f, 0.f, 0.f, 0.f};
      #pragma unroll 6
      for (int kt = 0; kt < 18; ++kt) {
        const int tap = kt >> 1, dy = tap / 3, dx = tap - dy * 3;
        const int pp = base0 + dy * 16 + dx;
        const int chb = (kt & 1) * 64 + lhi * 16;
        const f16x8 bf = *reinterpret_cast<const f16x8*>(
            hpadB + pp * 128 + (chb ^ ((pp & 7) << 4)));
        const f16x8 a0 = *reinterpret_cast<const f16x8*>(af0 + (size_t)kt * 512);
        const f16x8 a1 = *reinterpret_cast<const f16x8*>(af0 + (size_t)(18 + kt) * 512);
        acc0 = __builtin_amdgcn_mfma_f32_16x16x32_f16(a0, bf, acc0, 0, 0, 0);
        acc1 = __builtin_amdgcn_mfma_f32_16x16x32_f16(a1, bf, acc1, 0, 0, 0);
      }
      if (valid) {
        if (!isr) {
          #pragma unroll
          for (int mi = 0; mi < 2; ++mi) {
            const int ch0 = chbase + mi * 16 + lhi * 4;
            const f32x4 ac = mi ? acc1 : acc0;
            f16x4 zw;
            #pragma unroll
            for (int jj = 0; jj < 4; ++jj) {
              float pre = ac[jj] + wtv[mi][jj];
              zw[jj] = (_Float16)(1.0f / (1.0f + expf(-pre)));
            }
            *reinterpret_cast<f16x4*>(reinterpret_cast<char*>(zbuf) +
                p * 128 + ((ch0 * 2) ^ ((p & 7) << 4))) = zw;
          }
        } else {
          const int ppw = base0 + 17;
          #pragma unroll
          for (int mi = 0; mi < 2; ++mi) {
            const int ch0 = chbase + mi * 16 + lhi * 4;
            const f32x4 ac = mi ? acc1 : acc0;
            f16x4 rhw;
            #pragma unroll
            for (int jj = 0; jj < 4; ++jj) {
              float pre = ac[jj] + wtv[mi][jj];
              float r = 1.0f / (1.0f + expf(-pre));
              rhw[jj] = (_Float16)(r * h32[(ch0 + jj) * HW + pc]);
            }
            *reinterpret_cast<f16x4*>(reinterpret_cast<char*>(rhpad) +
                ppw * 128 + ((ch0 * 2) ^ ((ppw & 7) << 4))) = rhw;
          }
        }
      }
    }
    __syncthreads();

    // ================= phase 2: hh = tanh(wt + conv(rh,Uh)); update h ========
    for (int j = w; j < 26; j += 16) {
      const int pair2 = j & 1, nt = j >> 1;
      const int chbase = pair2 * 32;
      const int p = nt * 16 + l16;
      const int pc = (p < HW) ? p : (HW - 1);
      const bool valid = p < HW;
      const int py = pc / 14, px = pc - py * 14;
      const int base0 = py * 16 + px;

      float wtv[2][4];
      #pragma unroll
      for (int mi = 0; mi < 2; ++mi)
        #pragma unroll
        for (int jj = 0; jj < 4; ++jj)
          wtv[mi][jj] = wt[(chbase + mi * 16 + lhi * 4 + jj) * HW + pc];

      const _Float16* af0 = ufmt + ((size_t)(144 + pair2 * 36)) * 512 + lane * 8;
      f32x4 acc0 = {0.f, 0.f, 0.f, 0.f};
      f32x4 acc1 = {0.f, 0.f, 0.f, 0.f};
      #pragma unroll 6
      for (int kt = 0; kt < 18; ++kt) {
        const int tap = kt >> 1, dy = tap / 3, dx = tap - dy * 3;
        const int pp = base0 + dy * 16 + dx;
        const int chb = (kt & 1) * 64 + lhi * 16;
        const f16x8 bf = *reinterpret_cast<const f16x8*>(
            rhpadB + pp * 128 + (chb ^ ((pp & 7) << 4)));
        const f16x8 a0 = *reinterpret_cast<const f16x8*>(af0 + (size_t)kt * 512);
        const f16x8 a1 = *reinterpret_cast<const f16x8*>(af0 + (size_t)(18 + kt) * 512);
        acc0 = __builtin_amdgcn_mfma_f32_16x16x32_f16(a0, bf, acc0, 0, 0, 0);
        acc1 = __builtin_amdgcn_mfma_f32_16x16x32_f16(a1, bf, acc1, 0, 0, 0);
      }
      if (valid) {
        const int ppw = base0 + 17;
        #pragma unroll
        for (int mi = 0; mi < 2; ++mi) {
          const int ch0 = chbase + mi * 16 + lhi * 4;
          const f32x4 ac = mi ? acc1 : acc0;
          const f16x4 zv = *reinterpret_cast<const f16x4*>(
              reinterpret_cast<const char*>(zbuf) + p * 128 + ((ch0 * 2) ^ ((p & 7) << 4)));
          f16x4 hw;
          #pragma unroll
          for (int jj = 0; jj < 4; ++jj) {
            float hh = tanhf(ac[jj] + wtv[mi][jj]);
            float z = (float)zv[jj];
            float ho = h32[(ch0 + jj) * HW + pc];
            float hn = (1.0f - z) * hh + z * ho;
            h32[(ch0 + jj) * HW + pc] = hn;
            hw[jj] = (_Float16)hn;
            adest[((size_t)(b * T_STEPS + tw) * KC + ch0 + jj) * HW + pc] = (_Float16)hn;
          }
          *reinterpret_cast<f16x4*>(reinterpret_cast<char*>(hpad) +
              ppw * 128 + ((ch0 * 2) ^ ((ppw & 7) << 4))) = hw;
        }
      }
    }
    __syncthreads();
  }
}

// ---------------------------------------------------------------------------
// softmax over K=64 per (n,px): logits = a_f + a_b (fp16), output fp32.
// ---------------------------------------------------------------------------
__global__ __launch_bounds__(256)
void softmax_kernel(const _Float16* __restrict__ af, const _Float16* __restrict__ ab,
                    float* __restrict__ out) {
  int idx = blockIdx.x * 256 + threadIdx.x;
  int n = idx / HW, px = idx - n * HW;
  const _Float16* cf = af + (size_t)n * KC * HW + px;
  const _Float16* cb = ab + (size_t)n * KC * HW + px;
  float* co = out + (size_t)n * KC * HW + px;
  float v[KC];
  float mx = -3.4e38f;
  #pragma unroll
  for (int k = 0; k < KC; ++k) {
    v[k] = (float)cf[k * HW] + (float)cb[k * HW];
    mx = fmaxf(mx, v[k]);
  }
  float ssum = 0.0f;
  #pragma unroll
  for (int k = 0; k < KC; ++k) { v[k] = expf(v[k] - mx); ssum += v[k]; }
  float inv = 1.0f / ssum;
  #pragma unroll
  for (int k = 0; k < KC; ++k) co[k * HW] = v[k] * inv;
}

__global__ __launch_bounds__(256)
void sreduce_kernel(const float* __restrict__ a, float* __restrict__ S) {
  __shared__ float red[256];
  const int k = blockIdx.x, b = blockIdx.y, tid = threadIdx.x;
  const float* base = a + ((size_t)b * T_STEPS * KC + k) * HW;
  float sum = 0.0f;
  for (int i = tid; i < T_STEPS * HW; i += 256) {
    int t = i / HW, p = i - t * HW;
    sum += base[(size_t)t * KC * HW + p];
  }
  red[tid] = sum; __syncthreads();
  for (int st = 128; st > 0; st >>= 1) {
    if (tid < st) red[tid] += red[tid + st];
    __syncthreads();
  }
  if (tid == 0) S[b * KC + k] = red[0];
}

__global__ __launch_bounds__(256)
void vlad_gemm_kernel(const float* __restrict__ a, const float* __restrict__ xr,
                      float* __restrict__ Gpart) {
  __shared__ float sA[16][68];
  __shared__ float sX[16][68];
  const int tid = threadIdx.x;
  const int tx = tid & 15, ty = tid >> 4;
  const int d0 = blockIdx.x * 64;
  const int tc = blockIdx.y;
  const int b  = blockIdx.z;
  const int lr = tid >> 2;
  const int pq = (tid & 3) * 4;
  float acc[4][4] = {};

  for (int tt = 0; tt < 8; ++tt) {
    int n = b * T_STEPS + tc * 8 + tt;
    const float* an = a + (size_t)n * KC * HW;
    const float* xn = xr + (size_t)n * DD * HW;
    for (int p0 = 0; p0 < HW; p0 += 16) {
      __syncthreads();
      #pragma unroll
      for (int j = 0; j < 4; ++j) {
        int p = p0 + pq + j;
        sA[pq + j][lr] = (p < HW) ? an[lr * HW + p] : 0.0f;
        sX[pq + j][lr] = (p < HW) ? xn[(d0 + lr) * HW + p] : 0.0f;
      }
      __syncthreads();
      #pragma unroll
      for (int pp = 0; pp < 16; ++pp) {
        float4 av = *reinterpret_cast<const float4*>(&sA[pp][ty * 4]);
        float4 xv = *reinterpret_cast<const float4*>(&sX[pp][tx * 4]);
        float aa[4] = {av.x, av.y, av.z, av.w};
        float xx[4] = {xv.x, xv.y, xv.z, xv.w};
        #pragma unroll
        for (int i = 0; i < 4; ++i)
          #pragma unroll
          for (int j = 0; j < 4; ++j)
            acc[i][j] += aa[i] * xx[j];
      }
    }
  }
  float* gp = Gpart + ((size_t)(tc * NB + b) * KC) * DD;
  #pragma unroll
  for (int i = 0; i < 4; ++i)
    #pragma unroll
    for (int j = 0; j < 4; ++j)
      gp[(ty * 4 + i) * DD + d0 + tx * 4 + j] = acc[i][j];
}

__global__ __launch_bounds__(256)
void finalize1_kernel(const float* __restrict__ Gpart, const float* __restrict__ S,
                      const float* __restrict__ centers, float* __restrict__ out,
                      float* __restrict__ bsum) {
  __shared__ float red[256];
  const int k = blockIdx.x, b = blockIdx.y, tid = threadIdx.x;
  const float sv = S[b * KC + k];
  float vals[2];
  float ss = 0.0f;
  #pragma unroll
  for (int r = 0; r < 2; ++r) {
    int d = tid + r * 256;
    float g = 0.0f;
    #pragma unroll
    for (int tc = 0; tc < 4; ++tc)
      g += Gpart[((size_t)(tc * NB + b) * KC + k) * DD + d];
    float v = g - sv * centers[k * DD + d];
    vals[r] = v; ss += v * v;
  }
  red[tid] = ss; __syncthreads();
  for (int st = 128; st > 0; st >>= 1) {
    if (tid < st) red[tid] += red[tid + st];
    __syncthreads();
  }
  float tot = red[0];
  float inv = 1.0f / fmaxf(sqrtf(tot), 1e-12f);
  #pragma unroll
  for (int r = 0; r < 2; ++r) {
    int d = tid + r * 256;
    out[(size_t)b * KC * DD + k * DD + d] = vals[r] * inv;
  }
  if (tid == 0) atomicAdd(&bsum[b], tot * inv * inv);
}

__global__ __launch_bounds__(256)
void finalize2_kernel(float* __restrict__ out, const float* __restrict__ bsum) {
  int idx = blockIdx.x * 256 + threadIdx.x;
  int b = idx >> 15;
  out[idx] = out[idx] / fmaxf(sqrtf(bsum[b]), 1e-12f);
}

// ---------------------------------------------------------------------------
extern "C" void kernel_launch(void* const* d_in, const int* in_sizes, int n_in,
                              void* d_out, int out_size, void* d_ws, size_t ws_size,
                              hipStream_t stream) {
  const float* x       = (const float*)d_in[0];
  const float* redu_w  = (const float*)d_in[1];
  const float* redu_b  = (const float*)d_in[2];
  const float* share_w = (const float*)d_in[3];
  const float* share_b = (const float*)d_in[4];
  const float* Uz      = (const float*)d_in[5];
  const float* Ur      = (const float*)d_in[6];
  const float* Uh      = (const float*)d_in[7];
  const float* centers = (const float*)d_in[8];
  float* out = (float*)d_out;

  float* xr = (float*)d_ws;                                  // 256*512*196 f32
  float* wxb = xr + (size_t)NFR * DD * HW;                   // 256*64*196 f32
  _Float16* a_f = (_Float16*)(wxb + (size_t)NFR * KC * HW);  // 256*64*196 f16
  _Float16* a_b = a_f + (size_t)NFR * KC * HW;               // 256*64*196 f16
  float* Gpart = (float*)(a_b + (size_t)NFR * KC * HW);      // 4*8*64*512 f32
  float* S = Gpart + (size_t)4 * NB * KC * DD;               // 512
  float* bsum = S + 512;                                     // 8
  _Float16* ufmt = (_Float16*)(bsum + 8);                    // 216*512 f16
  float* assignc = wxb;  // combined softmax output overlays wxb (dead after GRU)

  hipMemsetAsync(bsum, 0, NB * sizeof(float), stream);

  // pre-format U weights into MFMA A-fragment layout (L2-resident, 216 KB)
  format_u<<<dim3(216), 64, 0, stream>>>(Uz, Ur, Uh, ufmt);

  // stage A: 1024 -> 512 reduction conv (fp16 MFMA)
  conv1x1_mfma<128><<<dim3(1024), 256, 0, stream>>>(x, redu_w, redu_b, xr, CIN, DD);
  // stage B: 512 -> 64 share conv (fp16 MFMA)
  conv1x1_mfma<64><<<dim3(256), 256, 0, stream>>>(xr, share_w, share_b, wxb, DD, KC);

  // GRU: 16 chain blocks x 16 waves, MFMA implicit GEMM, af streamed from L2
  gru_mfma16<<<dim3(16), 1024, 0, stream>>>(wxb, ufmt, a_f, a_b);

  softmax_kernel<<<dim3(196), 256, 0, stream>>>(a_f, a_b, assignc);
  sreduce_kernel<<<dim3(64, 8), 256, 0, stream>>>(assignc, S);
  vlad_gemm_kernel<<<dim3(8, 4, 8), 256, 0, stream>>>(assignc, xr, Gpart);
  finalize1_kernel<<<dim3(64, 8), 256, 0, stream>>>(Gpart, S, centers, out, bsum);
  finalize2_kernel<<<dim3(1024), 256, 0, stream>>>(out, bsum);
}

// Round 5
// 1220.402 us; speedup vs baseline: 6.7322x; 1.7283x over previous
//
#include <hip/hip_runtime.h>

#define HW 196
#define WIDTH 14
#define T_STEPS 32
#define KC 64      // centers / GRU channels
#define DD 512     // reduced dim
#define CIN 1024
#define NFR 256    // B*T
#define NB 8       // videos
#define NCOL (NFR * HW)   // 50176

using f16x8 = __attribute__((ext_vector_type(8))) _Float16;
using f16x4 = __attribute__((ext_vector_type(4))) _Float16;
using f32x4 = __attribute__((ext_vector_type(4))) float;

__device__ __forceinline__ void gload_lds16(const void* g, void* l) {
  __builtin_amdgcn_global_load_lds(
      (const __attribute__((address_space(1))) void*)g,
      (__attribute__((address_space(3))) void*)l, 16, 0, 0);
}

// ---------------------------------------------------------------------------
// f32 -> f16 elementwise convert (weights). nelem multiple of 4.
// ---------------------------------------------------------------------------
__global__ __launch_bounds__(256)
void cvt_f16(const float* __restrict__ src, _Float16* __restrict__ dst, int nelem) {
  int i = (blockIdx.x * 256 + threadIdx.x) * 4;
  if (i < nelem) {
    float4 v = *reinterpret_cast<const float4*>(src + i);
    f16x4 o;
    o[0] = (_Float16)v.x; o[1] = (_Float16)v.y;
    o[2] = (_Float16)v.z; o[3] = (_Float16)v.w;
    *reinterpret_cast<f16x4*>(dst + i) = o;
  }
}

// ---------------------------------------------------------------------------
// Transpose-convert x: (n, c, p) f32 -> xh[(n*196+p)][c] f16.
// Tile: one n, 64 c. LDS [64][197] f32 (stride 197 -> conflict-free).
// ---------------------------------------------------------------------------
__global__ __launch_bounds__(256)
void transpose_x(const float* __restrict__ x, _Float16* __restrict__ xh) {
  __shared__ float tile[64][197];
  const int tid = threadIdx.x;
  const int w = tid >> 6, lane = tid & 63;
  const int n = blockIdx.y;
  const int c0 = blockIdx.x * 64;
  const float* src = x + ((size_t)n * CIN + c0) * HW;
  // read: each wave covers 16 c-rows; 49 float4 per row
  for (int rr = 0; rr < 16; ++rr) {
    int c = w * 16 + rr;
    if (lane < 49) {
      float4 v = *reinterpret_cast<const float4*>(src + (size_t)c * HW + lane * 4);
      tile[c][lane * 4 + 0] = v.x; tile[c][lane * 4 + 1] = v.y;
      tile[c][lane * 4 + 2] = v.z; tile[c][lane * 4 + 3] = v.w;
    }
  }
  __syncthreads();
  // write: each pass, 4 waves write 4 p-rows of 64 c (128B each)
  _Float16* dst = xh + (size_t)n * HW * CIN + c0;
  for (int pp = 0; pp < 49; ++pp) {
    int p = w + pp * 4;
    dst[(size_t)p * CIN + lane] = (_Float16)tile[lane][p];
  }
}

// ---------------------------------------------------------------------------
// f16 MFMA GEMM: out[m][col] = bias[m] + sum_k A[m][k] * B[col][k]
// (both operands K-contiguous). BN=128 cols, BK=64, 4 waves (2m x 2n).
// global_load_lds staging with pre-swizzled source; T2 XOR swizzle on reads.
// WT: write outT[col][M] f16 (LDS-transposed, coalesced) -- stage A.
// !WT: write outNDP[(col/196)*M*196 + m*196 + col%196] f32 -- stage B.
// ---------------------------------------------------------------------------
template<int BM, int NMT, bool WT>
__global__ __launch_bounds__(256)
void gemm16(const _Float16* __restrict__ A, const _Float16* __restrict__ Bmat,
            const float* __restrict__ bias, float* __restrict__ outNDP,
            _Float16* __restrict__ outT, int M, int K) {
  constexpr int MF = BM / 32;
  union Smem {
    struct { _Float16 a[BM * 64]; _Float16 b[128 * 64]; } s;
    _Float16 t[WT ? 128 * 132 : 1];
  };
  __shared__ Smem u;

  const int tid = threadIdx.x;
  const int lane = tid & 63;
  const int w = tid >> 6;
  const int wm = w >> 1, wn = w & 1;
  const int l16 = lane & 15, lhi = lane >> 4;
  const int srow = lane >> 3, sslot = lane & 7;
  const int swz = (sslot ^ srow) << 4;        // pre-swizzled source byte offset
  const int mt = blockIdx.x & (NMT - 1);
  const int ct = blockIdx.x / NMT;
  const int m0 = mt * BM;
  const int col0 = ct * 128;

  f32x4 acc[MF][4];
  #pragma unroll
  for (int i = 0; i < MF; ++i)
    #pragma unroll
    for (int f = 0; f < 4; ++f) acc[i][f] = {0.f, 0.f, 0.f, 0.f};

  for (int k0 = 0; k0 < K; k0 += 64) {
    // stage A tile (BM x 64 f16) and B tile (128 x 64 f16), linear LDS,
    // swizzle folded into per-lane global source address (m201 pattern)
    #pragma unroll
    for (int s = 0; s < BM / 32; ++s) {
      int r = w * (BM / 4) + s * 8;
      gload_lds16((const char*)(A + (size_t)(m0 + r + srow) * K + k0) + swz,
                  (char*)u.s.a + r * 128);
    }
    #pragma unroll
    for (int s = 0; s < 4; ++s) {
      int r = w * 32 + s * 8;
      gload_lds16((const char*)(Bmat + (size_t)(col0 + r + srow) * K + k0) + swz,
                  (char*)u.s.b + r * 128);
    }
    __syncthreads();
    #pragma unroll
    for (int kk = 0; kk < 2; ++kk) {
      f16x8 af[MF];
      #pragma unroll
      for (int i = 0; i < MF; ++i) {
        int row = wm * (MF * 16) + i * 16 + l16;
        af[i] = *reinterpret_cast<const f16x8*>(
            (const char*)u.s.a + row * 128 + ((kk * 64 + lhi * 16) ^ ((row & 7) << 4)));
      }
      #pragma unroll
      for (int f = 0; f < 4; ++f) {
        int row = wn * 64 + f * 16 + l16;
        f16x8 bf = *reinterpret_cast<const f16x8*>(
            (const char*)u.s.b + row * 128 + ((kk * 64 + lhi * 16) ^ ((row & 7) << 4)));
        #pragma unroll
        for (int i = 0; i < MF; ++i)
          acc[i][f] = __builtin_amdgcn_mfma_f32_16x16x32_f16(af[i], bf, acc[i][f], 0, 0, 0);
      }
    }
    __syncthreads();
  }

  if constexpr (!WT) {
    // direct f32 write in (n, m, p) layout, bias added
    #pragma unroll
    for (int i = 0; i < MF; ++i) {
      int m = m0 + wm * (MF * 16) + i * 16 + lhi * 4;
      float b0 = bias[m], b1 = bias[m + 1], b2 = bias[m + 2], b3 = bias[m + 3];
      #pragma unroll
      for (int f = 0; f < 4; ++f) {
        int col = col0 + wn * 64 + f * 16 + l16;
        int n = col / HW, p = col - n * HW;
        float* o = outNDP + (size_t)n * M * HW + (size_t)m * HW + p;
        o[0] = acc[i][f][0] + b0;
        o[HW] = acc[i][f][1] + b1;
        o[2 * HW] = acc[i][f][2] + b2;
        o[3 * HW] = acc[i][f][3] + b3;
      }
    }
  } else {
    // transpose tile via LDS, write outT[col][M] f16 coalesced (BM==128)
    #pragma unroll
    for (int i = 0; i < MF; ++i) {
      int ml = wm * (MF * 16) + i * 16 + lhi * 4;
      int m = m0 + ml;
      float b0 = bias[m], b1 = bias[m + 1], b2 = bias[m + 2], b3 = bias[m + 3];
      #pragma unroll
      for (int f = 0; f < 4; ++f) {
        int cl = wn * 64 + f * 16 + l16;
        f16x4 v;
        v[0] = (_Float16)(acc[i][f][0] + b0);
        v[1] = (_Float16)(acc[i][f][1] + b1);
        v[2] = (_Float16)(acc[i][f][2] + b2);
        v[3] = (_Float16)(acc[i][f][3] + b3);
        *reinterpret_cast<f16x4*>((char*)u.t + cl * 264 + ml * 2) = v;
      }
    }
    __syncthreads();
    #pragma unroll
    for (int pass = 0; pass < 16; ++pass) {
      int row = (tid >> 5) + pass * 8;
      int coff = (tid & 31) * 4;
      f16x4 v = *reinterpret_cast<const f16x4*>((const char*)u.t + row * 264 + coff * 2);
      *reinterpret_cast<f16x4*>(outT + (size_t)(col0 + row) * M + m0 + coff) = v;
    }
  }
}

// ---------------------------------------------------------------------------
// Pre-format U weights into MFMA A-fragments (validated round 3).
// ---------------------------------------------------------------------------
__global__ __launch_bounds__(64)
void format_u(const float* __restrict__ Uz, const float* __restrict__ Ur,
              const float* __restrict__ Uh, _Float16* __restrict__ ufmt) {
  const int f = blockIdx.x;        // 0..215
  const int lane = threadIdx.x;
  const int l16 = lane & 15;
  const float* U;
  int ch, kt;
  if (f < 144) {
    int pair = f / 36, rem = f - pair * 36;
    int mi = rem / 18; kt = rem - mi * 18;
    U = (pair < 2) ? Uz : Ur;
    ch = (pair & 1) * 32 + mi * 16 + l16;
  } else {
    int g = f - 144;
    int pair = g / 36, rem = g - pair * 36;
    int mi = rem / 18; kt = rem - mi * 18;
    U = Uh;
    ch = pair * 32 + mi * 16 + l16;
  }
  const int tap = kt >> 1;
  const int k0 = (kt & 1) * 32 + (lane >> 4) * 8;
  f16x8 v;
  #pragma unroll
  for (int j = 0; j < 8; ++j)
    v[j] = (_Float16)U[(size_t)ch * 576 + (k0 + j) * 9 + tap];
  *reinterpret_cast<f16x8*>(ufmt + (size_t)f * 512 + lane * 8) = v;
}

// ---------------------------------------------------------------------------
// GRU via MFMA implicit GEMM, 16 waves/block, one block per chain (validated
// round 3).
// ---------------------------------------------------------------------------
__global__ __launch_bounds__(1024)
void gru_mfma16(const float* __restrict__ wxb, const _Float16* __restrict__ ufmt,
                _Float16* __restrict__ a_f, _Float16* __restrict__ a_b) {
  __shared__ __align__(16) _Float16 hpad[256 * 64];   // 32KB padded h
  __shared__ __align__(16) _Float16 rhpad[256 * 64];  // 32KB padded r*h
  __shared__ __align__(16) _Float16 zbuf[208 * 64];   // 26.6KB z
  __shared__ float h32[KC * HW];                      // 50KB fp32 h

  const int tid = threadIdx.x;
  const int lane = tid & 63;
  const int w = tid >> 6;          // wave 0..15
  const int l16 = lane & 15, lhi = lane >> 4;
  const int chain = blockIdx.x;
  const int b = chain >> 1, dir = chain & 1;

  for (int i = tid; i < 256 * 64; i += 1024) { hpad[i] = (_Float16)0.f; rhpad[i] = (_Float16)0.f; }
  for (int i = tid; i < KC * HW; i += 1024) h32[i] = 0.0f;
  __syncthreads();

  _Float16* adest = dir ? a_b : a_f;
  const char* hpadB = reinterpret_cast<const char*>(hpad);
  const char* rhpadB = reinterpret_cast<const char*>(rhpad);

  for (int t = 0; t < T_STEPS; ++t) {
    const int tw = dir ? (T_STEPS - 1 - t) : t;
    const float* wt = wxb + (size_t)(b * T_STEPS + tw) * KC * HW;

    // ================= phase 1: z (pair 0,1) / r (pair 2,3) =================
    for (int j = w; j < 52; j += 16) {
      const int pair = j & 3, nt = j >> 2;
      const bool isr = pair >= 2;
      const int chbase = (pair & 1) * 32;
      const int p = nt * 16 + l16;
      const int pc = (p < HW) ? p : (HW - 1);
      const bool valid = p < HW;
      const int py = pc / 14, px = pc - py * 14;
      const int base0 = py * 16 + px;

      float wtv[2][4];
      #pragma unroll
      for (int mi = 0; mi < 2; ++mi)
        #pragma unroll
        for (int jj = 0; jj < 4; ++jj)
          wtv[mi][jj] = wt[(chbase + mi * 16 + lhi * 4 + jj) * HW + pc];

      const _Float16* af0 = ufmt + ((size_t)pair * 36) * 512 + lane * 8;
      f32x4 acc0 = {0.f, 0.f, 0.f, 0.f};
      f32x4 acc1 = {0.f, 0.f, 0.f, 0.f};
      #pragma unroll 6
      for (int kt = 0; kt < 18; ++kt) {
        const int tap = kt >> 1, dy = tap / 3, dx = tap - dy * 3;
        const int pp = base0 + dy * 16 + dx;
        const int chb = (kt & 1) * 64 + lhi * 16;
        const f16x8 bf = *reinterpret_cast<const f16x8*>(
            hpadB + pp * 128 + (chb ^ ((pp & 7) << 4)));
        const f16x8 a0 = *reinterpret_cast<const f16x8*>(af0 + (size_t)kt * 512);
        const f16x8 a1 = *reinterpret_cast<const f16x8*>(af0 + (size_t)(18 + kt) * 512);
        acc0 = __builtin_amdgcn_mfma_f32_16x16x32_f16(a0, bf, acc0, 0, 0, 0);
        acc1 = __builtin_amdgcn_mfma_f32_16x16x32_f16(a1, bf, acc1, 0, 0, 0);
      }
      if (valid) {
        if (!isr) {
          #pragma unroll
          for (int mi = 0; mi < 2; ++mi) {
            const int ch0 = chbase + mi * 16 + lhi * 4;
            const f32x4 ac = mi ? acc1 : acc0;
            f16x4 zw;
            #pragma unroll
            for (int jj = 0; jj < 4; ++jj) {
              float pre = ac[jj] + wtv[mi][jj];
              zw[jj] = (_Float16)(1.0f / (1.0f + expf(-pre)));
            }
            *reinterpret_cast<f16x4*>(reinterpret_cast<char*>(zbuf) +
                p * 128 + ((ch0 * 2) ^ ((p & 7) << 4))) = zw;
          }
        } else {
          const int ppw = base0 + 17;
          #pragma unroll
          for (int mi = 0; mi < 2; ++mi) {
            const int ch0 = chbase + mi * 16 + lhi * 4;
            const f32x4 ac = mi ? acc1 : acc0;
            f16x4 rhw;
            #pragma unroll
            for (int jj = 0; jj < 4; ++jj) {
              float pre = ac[jj] + wtv[mi][jj];
              float r = 1.0f / (1.0f + expf(-pre));
              rhw[jj] = (_Float16)(r * h32[(ch0 + jj) * HW + pc]);
            }
            *reinterpret_cast<f16x4*>(reinterpret_cast<char*>(rhpad) +
                ppw * 128 + ((ch0 * 2) ^ ((ppw & 7) << 4))) = rhw;
          }
        }
      }
    }
    __syncthreads();

    // ================= phase 2: hh = tanh(wt + conv(rh,Uh)); update h ========
    for (int j = w; j < 26; j += 16) {
      const int pair2 = j & 1, nt = j >> 1;
      const int chbase = pair2 * 32;
      const int p = nt * 16 + l16;
      const int pc = (p < HW) ? p : (HW - 1);
      const bool valid = p < HW;
      const int py = pc / 14, px = pc - py * 14;
      const int base0 = py * 16 + px;

      float wtv[2][4];
      #pragma unroll
      for (int mi = 0; mi < 2; ++mi)
        #pragma unroll
        for (int jj = 0; jj < 4; ++jj)
          wtv[mi][jj] = wt[(chbase + mi * 16 + lhi * 4 + jj) * HW + pc];

      const _Float16* af0 = ufmt + ((size_t)(144 + pair2 * 36)) * 512 + lane * 8;
      f32x4 acc0 = {0.f, 0.f, 0.f, 0.f};
      f32x4 acc1 = {0.f, 0.f, 0.f, 0.f};
      #pragma unroll 6
      for (int kt = 0; kt < 18; ++kt) {
        const int tap = kt >> 1, dy = tap / 3, dx = tap - dy * 3;
        const int pp = base0 + dy * 16 + dx;
        const int chb = (kt & 1) * 64 + lhi * 16;
        const f16x8 bf = *reinterpret_cast<const f16x8*>(
            rhpadB + pp * 128 + (chb ^ ((pp & 7) << 4)));
        const f16x8 a0 = *reinterpret_cast<const f16x8*>(af0 + (size_t)kt * 512);
        const f16x8 a1 = *reinterpret_cast<const f16x8*>(af0 + (size_t)(18 + kt) * 512);
        acc0 = __builtin_amdgcn_mfma_f32_16x16x32_f16(a0, bf, acc0, 0, 0, 0);
        acc1 = __builtin_amdgcn_mfma_f32_16x16x32_f16(a1, bf, acc1, 0, 0, 0);
      }
      if (valid) {
        const int ppw = base0 + 17;
        #pragma unroll
        for (int mi = 0; mi < 2; ++mi) {
          const int ch0 = chbase + mi * 16 + lhi * 4;
          const f32x4 ac = mi ? acc1 : acc0;
          const f16x4 zv = *reinterpret_cast<const f16x4*>(
              reinterpret_cast<const char*>(zbuf) + p * 128 + ((ch0 * 2) ^ ((p & 7) << 4)));
          f16x4 hw;
          #pragma unroll
          for (int jj = 0; jj < 4; ++jj) {
            float hh = tanhf(ac[jj] + wtv[mi][jj]);
            float z = (float)zv[jj];
            float ho = h32[(ch0 + jj) * HW + pc];
            float hn = (1.0f - z) * hh + z * ho;
            h32[(ch0 + jj) * HW + pc] = hn;
            hw[jj] = (_Float16)hn;
            adest[((size_t)(b * T_STEPS + tw) * KC + ch0 + jj) * HW + pc] = (_Float16)hn;
          }
          *reinterpret_cast<f16x4*>(reinterpret_cast<char*>(hpad) +
              ppw * 128 + ((ch0 * 2) ^ ((ppw & 7) << 4))) = hw;
        }
      }
    }
    __syncthreads();
  }
}

// ---------------------------------------------------------------------------
// softmax over K=64 per (n,px): logits = a_f + a_b (fp16), output fp32.
// ---------------------------------------------------------------------------
__global__ __launch_bounds__(256)
void softmax_kernel(const _Float16* __restrict__ af, const _Float16* __restrict__ ab,
                    float* __restrict__ out) {
  int idx = blockIdx.x * 256 + threadIdx.x;
  int n = idx / HW, px = idx - n * HW;
  const _Float16* cf = af + (size_t)n * KC * HW + px;
  const _Float16* cb = ab + (size_t)n * KC * HW + px;
  float* co = out + (size_t)n * KC * HW + px;
  float v[KC];
  float mx = -3.4e38f;
  #pragma unroll
  for (int k = 0; k < KC; ++k) {
    v[k] = (float)cf[k * HW] + (float)cb[k * HW];
    mx = fmaxf(mx, v[k]);
  }
  float ssum = 0.0f;
  #pragma unroll
  for (int k = 0; k < KC; ++k) { v[k] = expf(v[k] - mx); ssum += v[k]; }
  float inv = 1.0f / ssum;
  #pragma unroll
  for (int k = 0; k < KC; ++k) co[k * HW] = v[k] * inv;
}

__global__ __launch_bounds__(256)
void sreduce_kernel(const float* __restrict__ a, float* __restrict__ S) {
  __shared__ float red[256];
  const int k = blockIdx.x, b = blockIdx.y, tid = threadIdx.x;
  const float* base = a + ((size_t)b * T_STEPS * KC + k) * HW;
  float sum = 0.0f;
  for (int i = tid; i < T_STEPS * HW; i += 256) {
    int t = i / HW, p = i - t * HW;
    sum += base[(size_t)t * KC * HW + p];
  }
  red[tid] = sum; __syncthreads();
  for (int st = 128; st > 0; st >>= 1) {
    if (tid < st) red[tid] += red[tid + st];
    __syncthreads();
  }
  if (tid == 0) S[b * KC + k] = red[0];
}

// ---------------------------------------------------------------------------
// VLAD GEMM partials; xr now f16 in [col][512] layout (xrh).
// ---------------------------------------------------------------------------
__global__ __launch_bounds__(256)
void vlad_gemm_kernel(const float* __restrict__ a, const _Float16* __restrict__ xrh,
                      float* __restrict__ Gpart) {
  __shared__ float sA[16][68];
  __shared__ float sX[16][68];
  const int tid = threadIdx.x;
  const int tx = tid & 15, ty = tid >> 4;
  const int d0 = blockIdx.x * 64;
  const int tc = blockIdx.y;
  const int b  = blockIdx.z;
  const int lr = tid >> 2;
  const int pq = (tid & 3) * 4;
  float acc[4][4] = {};

  for (int tt = 0; tt < 8; ++tt) {
    int n = b * T_STEPS + tc * 8 + tt;
    const float* an = a + (size_t)n * KC * HW;
    const _Float16* xn = xrh + (size_t)n * HW * DD;
    for (int p0 = 0; p0 < HW; p0 += 16) {
      __syncthreads();
      #pragma unroll
      for (int j = 0; j < 4; ++j) {
        int p = p0 + pq + j;
        sA[pq + j][lr] = (p < HW) ? an[lr * HW + p] : 0.0f;
        sX[pq + j][lr] = (p < HW) ? (float)xn[(size_t)p * DD + d0 + lr] : 0.0f;
      }
      __syncthreads();
      #pragma unroll
      for (int pp = 0; pp < 16; ++pp) {
        float4 av = *reinterpret_cast<const float4*>(&sA[pp][ty * 4]);
        float4 xv = *reinterpret_cast<const float4*>(&sX[pp][tx * 4]);
        float aa[4] = {av.x, av.y, av.z, av.w};
        float xx[4] = {xv.x, xv.y, xv.z, xv.w};
        #pragma unroll
        for (int i = 0; i < 4; ++i)
          #pragma unroll
          for (int j = 0; j < 4; ++j)
            acc[i][j] += aa[i] * xx[j];
      }
    }
  }
  float* gp = Gpart + ((size_t)(tc * NB + b) * KC) * DD;
  #pragma unroll
  for (int i = 0; i < 4; ++i)
    #pragma unroll
    for (int j = 0; j < 4; ++j)
      gp[(ty * 4 + i) * DD + d0 + tx * 4 + j] = acc[i][j];
}

__global__ __launch_bounds__(256)
void finalize1_kernel(const float* __restrict__ Gpart, const float* __restrict__ S,
                      const float* __restrict__ centers, float* __restrict__ out,
                      float* __restrict__ bsum) {
  __shared__ float red[256];
  const int k = blockIdx.x, b = blockIdx.y, tid = threadIdx.x;
  const float sv = S[b * KC + k];
  float vals[2];
  float ss = 0.0f;
  #pragma unroll
  for (int r = 0; r < 2; ++r) {
    int d = tid + r * 256;
    float g = 0.0f;
    #pragma unroll
    for (int tc = 0; tc < 4; ++tc)
      g += Gpart[((size_t)(tc * NB + b) * KC + k) * DD + d];
    float v = g - sv * centers[k * DD + d];
    vals[r] = v; ss += v * v;
  }
  red[tid] = ss; __syncthreads();
  for (int st = 128; st > 0; st >>= 1) {
    if (tid < st) red[tid] += red[tid + st];
    __syncthreads();
  }
  float tot = red[0];
  float inv = 1.0f / fmaxf(sqrtf(tot), 1e-12f);
  #pragma unroll
  for (int r = 0; r < 2; ++r) {
    int d = tid + r * 256;
    out[(size_t)b * KC * DD + k * DD + d] = vals[r] * inv;
  }
  if (tid == 0) atomicAdd(&bsum[b], tot * inv * inv);
}

__global__ __launch_bounds__(256)
void finalize2_kernel(float* __restrict__ out, const float* __restrict__ bsum) {
  int idx = blockIdx.x * 256 + threadIdx.x;
  int b = idx >> 15;
  out[idx] = out[idx] / fmaxf(sqrtf(bsum[b]), 1e-12f);
}

// ---------------------------------------------------------------------------
extern "C" void kernel_launch(void* const* d_in, const int* in_sizes, int n_in,
                              void* d_out, int out_size, void* d_ws, size_t ws_size,
                              hipStream_t stream) {
  const float* x       = (const float*)d_in[0];
  const float* redu_w  = (const float*)d_in[1];
  const float* redu_b  = (const float*)d_in[2];
  const float* share_w = (const float*)d_in[3];
  const float* share_b = (const float*)d_in[4];
  const float* Uz      = (const float*)d_in[5];
  const float* Ur      = (const float*)d_in[6];
  const float* Uh      = (const float*)d_in[7];
  const float* centers = (const float*)d_in[8];
  float* out = (float*)d_out;

  // workspace layout (~173 MB, matches round-3 footprint)
  float* wxb = (float*)d_ws;                                // 3.21M f32 (12.85MB); assignc overlay
  _Float16* xh = (_Float16*)(wxb + (size_t)NFR * KC * HW);  // 51.38M f16 (102.8MB)
  _Float16* a_f = xh;                                       // overlay (xh dead before GRU writes)
  _Float16* a_b = a_f + (size_t)NFR * KC * HW;
  _Float16* xrh = xh + (size_t)NCOL * CIN;                  // 25.69M f16 (51.4MB)
  float* Gpart = (float*)(xrh + (size_t)NCOL * DD);         // 1.05M f32
  float* S = Gpart + (size_t)4 * NB * KC * DD;              // 512
  float* bsum = S + 512;                                    // 8
  _Float16* ufmt = (_Float16*)(bsum + 8);                   // 110592 f16
  _Float16* wh = ufmt + 216 * 512;                          // 524288 f16
  _Float16* swh = wh + (size_t)DD * CIN;                    // 32768 f16
  float* assignc = wxb;

  hipMemsetAsync(bsum, 0, NB * sizeof(float), stream);

  // weight converts + U pre-format + x transpose-convert
  cvt_f16<<<dim3(512), 256, 0, stream>>>(redu_w, wh, DD * CIN);
  cvt_f16<<<dim3(32), 256, 0, stream>>>(share_w, swh, KC * DD);
  format_u<<<dim3(216), 64, 0, stream>>>(Uz, Ur, Uh, ufmt);
  transpose_x<<<dim3(16, 256), 256, 0, stream>>>(x, xh);

  // stage A: [512 x 50176] = wh[512x1024] * xh[50176x1024]^T -> xrh f16 [col][512]
  gemm16<128, 4, true><<<dim3(392 * 4), 256, 0, stream>>>(
      wh, xh, redu_b, nullptr, xrh, DD, CIN);
  // stage B: [64 x 50176] = swh[64x512] * xrh^T -> wxb f32 (n,k,p)
  gemm16<64, 1, false><<<dim3(392), 256, 0, stream>>>(
      swh, xrh, share_b, wxb, nullptr, KC, DD);

  // GRU: 16 chain blocks x 16 waves (validated round 3)
  gru_mfma16<<<dim3(16), 1024, 0, stream>>>(wxb, ufmt, a_f, a_b);

  softmax_kernel<<<dim3(196), 256, 0, stream>>>(a_f, a_b, assignc);
  sreduce_kernel<<<dim3(64, 8), 256, 0, stream>>>(assignc, S);
  vlad_gemm_kernel<<<dim3(8, 4, 8), 256, 0, stream>>>(assignc, xrh, Gpart);
  finalize1_kernel<<<dim3(64, 8), 256, 0, stream>>>(Gpart, S, centers, out, bsum);
  finalize2_kernel<<<dim3(1024), 256, 0, stream>>>(out, bsum);
}